// Round 1
// baseline (4296.633 us; speedup 1.0000x reference)
//
#include <hip/hip_runtime.h>
#include <hip/hip_bf16.h>

// ---------------------------------------------------------------------------
// MoE top-2 FFN, MI355X baseline (round 1): sparse routing + fp32 tiled GEMMs.
// T=8192 tokens, D=1024, H=4096, E=8 experts, top_k=2, exact-erf GELU.
//
// Pipeline:
//   zero_kernel   : zero d_out (poisoned 0xAA) + expert counters
//   gate_kernel   : 1 wave/token -> logits(8), softmax, top-2, append to
//                   per-expert token lists (atomic)
//   offs_kernel   : exclusive prefix sum of counts -> compact H-row offsets
//   ffn1_kernel   : gathered-A GEMM  [n_e x 1024] @ [1024 x 4096] + b1, GELU
//                   -> Hbuf (compact rows)
//   ffn2_kernel   : compact-A GEMM   [n_e x 4096] @ [4096 x 1024] + b2,
//                   * gate prob, atomicAdd into out rows
//
// GEMM tile: 128x128, BK=16, 256 threads, 8x8 per-thread acc (fp32 vector FMA
// -- no fp32-input MFMA on CDNA4). Hbuf fp32 (256MB) if ws allows, else bf16.
// ---------------------------------------------------------------------------

#define T_TOK 8192
#define DDIM  1024
#define HDIM  4096
#define NEXP  8

__device__ __forceinline__ float gelu_erf(float v) {
    return 0.5f * v * (1.0f + erff(v * 0.70710678118654752f));
}

// bf16 bit helpers (avoid API-name drift; RNE rounding)
__device__ __forceinline__ float bfbits2f(unsigned short u) {
    unsigned int x = ((unsigned int)u) << 16;
    float f; __builtin_memcpy(&f, &x, 4); return f;
}
__device__ __forceinline__ unsigned short f2bfbits(float f) {
    unsigned int x; __builtin_memcpy(&x, &f, 4);
    x += 0x7fffu + ((x >> 16) & 1u);
    return (unsigned short)(x >> 16);
}

template <typename HT> struct HIO;
template <> struct HIO<float> {
    static __device__ __forceinline__ float4 ld4(const float* p) { return *(const float4*)p; }
    static __device__ __forceinline__ void st8(float* p, const float* v) {
        *(float4*)p       = make_float4(v[0], v[1], v[2], v[3]);
        *(float4*)(p + 4) = make_float4(v[4], v[5], v[6], v[7]);
    }
};
template <> struct HIO<__hip_bfloat16> {
    static __device__ __forceinline__ float4 ld4(const __hip_bfloat16* p) {
        ushort4 u = *(const ushort4*)p;
        float4 r; r.x = bfbits2f(u.x); r.y = bfbits2f(u.y);
        r.z = bfbits2f(u.z); r.w = bfbits2f(u.w);
        return r;
    }
    static __device__ __forceinline__ void st8(__hip_bfloat16* p, const float* v) {
        ushort4 a, b;
        a.x = f2bfbits(v[0]); a.y = f2bfbits(v[1]); a.z = f2bfbits(v[2]); a.w = f2bfbits(v[3]);
        b.x = f2bfbits(v[4]); b.y = f2bfbits(v[5]); b.z = f2bfbits(v[6]); b.w = f2bfbits(v[7]);
        *(ushort4*)p       = a;
        *(ushort4*)(p + 4) = b;
    }
};

// ---------------------------------------------------------------------------
__global__ __launch_bounds__(256) void zero_kernel(float* __restrict__ out,
                                                   int n, int* __restrict__ counts) {
    int i = blockIdx.x * 256 + threadIdx.x;
    if (i < n) out[i] = 0.0f;
    if (blockIdx.x == 0 && threadIdx.x < 16) counts[threadIdx.x] = 0;
}

// one wave per token: logits = x_row @ gate_w + gate_b; softmax; top-2
__global__ __launch_bounds__(256) void gate_kernel(
    const float* __restrict__ x, const float* __restrict__ gw,
    const float* __restrict__ gb, int* __restrict__ counts,
    int* __restrict__ tok_idx, float* __restrict__ tok_gate) {
    const int token = blockIdx.x * 4 + (threadIdx.x >> 6);
    const int lane  = threadIdx.x & 63;
    const float* xr = x + (size_t)token * DDIM;

    float acc[8] = {0.f, 0.f, 0.f, 0.f, 0.f, 0.f, 0.f, 0.f};
    for (int d = lane; d < DDIM; d += 64) {
        const float xv = xr[d];
        const float4 g0 = *(const float4*)(gw + d * NEXP);
        const float4 g1 = *(const float4*)(gw + d * NEXP + 4);
        acc[0] = fmaf(xv, g0.x, acc[0]); acc[1] = fmaf(xv, g0.y, acc[1]);
        acc[2] = fmaf(xv, g0.z, acc[2]); acc[3] = fmaf(xv, g0.w, acc[3]);
        acc[4] = fmaf(xv, g1.x, acc[4]); acc[5] = fmaf(xv, g1.y, acc[5]);
        acc[6] = fmaf(xv, g1.z, acc[6]); acc[7] = fmaf(xv, g1.w, acc[7]);
    }
#pragma unroll
    for (int e = 0; e < 8; ++e)
        for (int off = 32; off > 0; off >>= 1)
            acc[e] += __shfl_down(acc[e], off);

    if (lane == 0) {
#pragma unroll
        for (int e = 0; e < 8; ++e) acc[e] += gb[e];
        float m = acc[0];
#pragma unroll
        for (int e = 1; e < 8; ++e) m = fmaxf(m, acc[e]);
        float p[8], s = 0.f;
#pragma unroll
        for (int e = 0; e < 8; ++e) { p[e] = expf(acc[e] - m); s += p[e]; }
        const float inv = 1.0f / s;
#pragma unroll
        for (int e = 0; e < 8; ++e) p[e] *= inv;
        // top-2, ties -> lowest index (matches jax.lax.top_k)
        int i1 = 0;
#pragma unroll
        for (int e = 1; e < 8; ++e) if (p[e] > p[i1]) i1 = e;
        int i2 = (i1 == 0) ? 1 : 0;
#pragma unroll
        for (int e = 0; e < 8; ++e) if (e != i1 && p[e] > p[i2]) i2 = e;

        int pos1 = atomicAdd(&counts[i1], 1);
        tok_idx[i1 * T_TOK + pos1]  = token;
        tok_gate[i1 * T_TOK + pos1] = p[i1];
        int pos2 = atomicAdd(&counts[i2], 1);
        tok_idx[i2 * T_TOK + pos2]  = token;
        tok_gate[i2 * T_TOK + pos2] = p[i2];
    }
}

__global__ void offs_kernel(const int* __restrict__ counts, int* __restrict__ offs) {
    if (threadIdx.x == 0 && blockIdx.x == 0) {
        int s = 0;
#pragma unroll
        for (int e = 0; e < NEXP; ++e) { offs[e] = s; s += counts[e]; }
        offs[NEXP] = s;
    }
}

// ---------------------------------------------------------------------------
// FFN1: C[m, n] = gelu( sum_k x[tok[m], k] * w1[e][k, n] + b1[e][n] )
template <typename HT>
__global__ __launch_bounds__(256) void ffn1_kernel(
    const float* __restrict__ x, const float* __restrict__ w1,
    const float* __restrict__ b1, const int* __restrict__ counts,
    const int* __restrict__ offs, const int* __restrict__ tok_idx,
    HT* __restrict__ Hbuf) {
    const int e   = blockIdx.z;
    const int cnt = counts[e];
    const int m0  = blockIdx.y * 128;
    if (m0 >= cnt) return;
    const int n0  = blockIdx.x * 128;

    __shared__ __align__(16) float As[16][136];  // [k][m], +8 pad keeps 16B align
    __shared__ __align__(16) float Bs[16][136];  // [k][n]
    __shared__ int stok[128];

    const int tid = threadIdx.x;
    if (tid < 128) stok[tid] = tok_idx[e * T_TOK + min(m0 + tid, cnt - 1)];
    __syncthreads();

    const float* W = w1 + (size_t)e * DDIM * HDIM;

    float acc[8][8];
#pragma unroll
    for (int i = 0; i < 8; ++i)
#pragma unroll
        for (int j = 0; j < 8; ++j) acc[i][j] = 0.f;

    const int tm  = tid & 15, tn = tid >> 4;
    const int arA = tid >> 2, acA = (tid & 3) * 4;   // A-tile slots (2 per thread)
    const int bkB = tid >> 5, bcB = (tid & 31) * 4;  // B-tile slots (2 per thread)

    for (int k0 = 0; k0 < DDIM; k0 += 16) {
#pragma unroll
        for (int h = 0; h < 2; ++h) {
            const int r = arA + h * 64;
            const float4 v = *(const float4*)(x + (size_t)stok[r] * DDIM + k0 + acA);
            As[acA + 0][r] = v.x; As[acA + 1][r] = v.y;
            As[acA + 2][r] = v.z; As[acA + 3][r] = v.w;
        }
#pragma unroll
        for (int h = 0; h < 2; ++h) {
            const int kr = bkB + h * 8;
            *(float4*)&Bs[kr][bcB] = *(const float4*)(W + (size_t)(k0 + kr) * HDIM + n0 + bcB);
        }
        __syncthreads();
#pragma unroll
        for (int kk = 0; kk < 16; ++kk) {
            float a[8], b[8];
            *(float4*)&a[0] = *(const float4*)&As[kk][tm * 8];
            *(float4*)&a[4] = *(const float4*)&As[kk][tm * 8 + 4];
            *(float4*)&b[0] = *(const float4*)&Bs[kk][tn * 8];
            *(float4*)&b[4] = *(const float4*)&Bs[kk][tn * 8 + 4];
#pragma unroll
            for (int i = 0; i < 8; ++i)
#pragma unroll
                for (int j = 0; j < 8; ++j)
                    acc[i][j] = fmaf(a[i], b[j], acc[i][j]);
        }
        __syncthreads();
    }

    const int hbase = offs[e] + m0;
#pragma unroll
    for (int i = 0; i < 8; ++i) {
        const int row = tm * 8 + i;
        if (m0 + row < cnt) {
            float v[8];
#pragma unroll
            for (int j = 0; j < 8; ++j)
                v[j] = gelu_erf(acc[i][j] + b1[e * HDIM + n0 + tn * 8 + j]);
            HIO<HT>::st8(Hbuf + (size_t)(hbase + row) * HDIM + n0 + tn * 8, v);
        }
    }
}

// FFN2: out[tok[m], n] += g[m] * ( sum_k H[m, k] * w2[e][k, n] + b2[e][n] )
template <typename HT>
__global__ __launch_bounds__(256) void ffn2_kernel(
    const HT* __restrict__ Hbuf, const float* __restrict__ w2,
    const float* __restrict__ b2, const int* __restrict__ counts,
    const int* __restrict__ offs, const int* __restrict__ tok_idx,
    const float* __restrict__ tok_gate, float* __restrict__ out) {
    const int e   = blockIdx.z;
    const int cnt = counts[e];
    const int m0  = blockIdx.y * 128;
    if (m0 >= cnt) return;
    const int n0  = blockIdx.x * 128;

    __shared__ __align__(16) float As[16][136];
    __shared__ __align__(16) float Bs[16][136];

    const int tid = threadIdx.x;
    const HT* Arows = Hbuf + (size_t)(offs[e] + m0) * HDIM;
    const float* W  = w2 + (size_t)e * HDIM * DDIM;

    float acc[8][8];
#pragma unroll
    for (int i = 0; i < 8; ++i)
#pragma unroll
        for (int j = 0; j < 8; ++j) acc[i][j] = 0.f;

    const int tm  = tid & 15, tn = tid >> 4;
    const int arA = tid >> 2, acA = (tid & 3) * 4;
    const int bkB = tid >> 5, bcB = (tid & 31) * 4;

    for (int k0 = 0; k0 < HDIM; k0 += 16) {
#pragma unroll
        for (int h = 0; h < 2; ++h) {
            const int r    = arA + h * 64;
            const int reff = min(m0 + r, cnt - 1) - m0;  // clamp: stay inside this expert
            const float4 v = HIO<HT>::ld4(Arows + (size_t)reff * HDIM + k0 + acA);
            As[acA + 0][r] = v.x; As[acA + 1][r] = v.y;
            As[acA + 2][r] = v.z; As[acA + 3][r] = v.w;
        }
#pragma unroll
        for (int h = 0; h < 2; ++h) {
            const int kr = bkB + h * 8;
            *(float4*)&Bs[kr][bcB] = *(const float4*)(W + (size_t)(k0 + kr) * DDIM + n0 + bcB);
        }
        __syncthreads();
#pragma unroll
        for (int kk = 0; kk < 16; ++kk) {
            float a[8], b[8];
            *(float4*)&a[0] = *(const float4*)&As[kk][tm * 8];
            *(float4*)&a[4] = *(const float4*)&As[kk][tm * 8 + 4];
            *(float4*)&b[0] = *(const float4*)&Bs[kk][tn * 8];
            *(float4*)&b[4] = *(const float4*)&Bs[kk][tn * 8 + 4];
#pragma unroll
            for (int i = 0; i < 8; ++i)
#pragma unroll
                for (int j = 0; j < 8; ++j)
                    acc[i][j] = fmaf(a[i], b[j], acc[i][j]);
        }
        __syncthreads();
    }

#pragma unroll
    for (int i = 0; i < 8; ++i) {
        const int row = tm * 8 + i;
        const int m   = m0 + row;
        if (m < cnt) {
            const int   t = tok_idx[e * T_TOK + m];
            const float g = tok_gate[e * T_TOK + m];
            float* orow = out + (size_t)t * DDIM + n0 + tn * 8;
#pragma unroll
            for (int j = 0; j < 8; ++j) {
                const float val = g * (acc[i][j] + b2[e * DDIM + n0 + tn * 8 + j]);
                atomicAdd(orow + j, val);
            }
        }
    }
}

// ---------------------------------------------------------------------------
extern "C" void kernel_launch(void* const* d_in, const int* in_sizes, int n_in,
                              void* d_out, int out_size, void* d_ws, size_t ws_size,
                              hipStream_t stream) {
    const float* x      = (const float*)d_in[0];
    const float* gate_w = (const float*)d_in[1];
    const float* gate_b = (const float*)d_in[2];
    const float* w1     = (const float*)d_in[3];
    const float* b1     = (const float*)d_in[4];
    const float* w2     = (const float*)d_in[5];
    const float* b2     = (const float*)d_in[6];
    // d_in[7] = top_k (fixed at 2)

    char* ws       = (char*)d_ws;
    int*   counts  = (int*)ws;                       // 8 ints (zeroed)
    int*   offs    = (int*)(ws + 64);                // 9 ints
    int*   tok_idx = (int*)(ws + 1024);              // [E][T] ints, 256KB
    float* tok_gate= (float*)(ws + 1024 + 262144);   // [E][T] floats, 256KB
    void*  Hbuf    = (void*)(ws + (1 << 20));        // compact H rows

    const size_t need_f32 = (size_t)(1 << 20) + (size_t)16384 * HDIM * sizeof(float);
    const bool hf32 = ws_size >= need_f32;

    float* out = (float*)d_out;

    zero_kernel<<<(T_TOK * DDIM + 255) / 256, 256, 0, stream>>>(out, T_TOK * DDIM, counts);
    gate_kernel<<<T_TOK / 4, 256, 0, stream>>>(x, gate_w, gate_b, counts, tok_idx, tok_gate);
    offs_kernel<<<1, 64, 0, stream>>>(counts, offs);

    dim3 g1(HDIM / 128, T_TOK / 128, NEXP);
    dim3 g2(DDIM / 128, T_TOK / 128, NEXP);
    if (hf32) {
        ffn1_kernel<float><<<g1, 256, 0, stream>>>(x, w1, b1, counts, offs, tok_idx, (float*)Hbuf);
        ffn2_kernel<float><<<g2, 256, 0, stream>>>((const float*)Hbuf, w2, b2, counts, offs,
                                                   tok_idx, tok_gate, out);
    } else {
        ffn1_kernel<__hip_bfloat16><<<g1, 256, 0, stream>>>(x, w1, b1, counts, offs, tok_idx,
                                                            (__hip_bfloat16*)Hbuf);
        ffn2_kernel<__hip_bfloat16><<<g2, 256, 0, stream>>>((const __hip_bfloat16*)Hbuf, w2, b2,
                                                            counts, offs, tok_idx, tok_gate, out);
    }
}

// Round 6
// 1817.611 us; speedup vs baseline: 2.3639x; 2.3639x over previous
//
#include <hip/hip_runtime.h>
#include <hip/hip_bf16.h>

// ---------------------------------------------------------------------------
// MoE top-2 FFN, MI355X round 6 (= round 2 design, resubmit; 4x infra timeout).
// Sparse routing + split-bf16 MFMA GEMMs.
// T=8192 tokens, D=1024, H=4096, E=8 experts, top_k=2, exact-erf GELU.
//
//   zero_kernel : zero d_out + expert counters
//   gate_kernel : 1 wave/token -> softmax, top-2, per-expert token lists
//   offs_kernel : prefix sum -> compact H-row offsets
//   ffn1_mfma   : [cnt x 1024]@[1024 x 4096]+b1, GELU -> Hbuf (bf16 compact)
//                 A = x split hi/lo bf16 (on-the-fly), B = w1 split hi/lo
//                 3-term MFMA (hh + hl + lh) ~ fp32 accuracy
//   ffn2_mfma   : [cnt x 4096]@[4096 x 1024]+b2, *gate, atomicAdd into out
//                 A = Hbuf bf16 (exact), B = w2 split hi/lo, 2-term MFMA
//
// MFMA 16x16x32 bf16. Tile 128x128, BK=32, 256 thr (4 waves, each 64x64).
// LDS tiles are [row][32] bf16 (64B rows). ws = 1MB meta + 128MB Hbuf
// (proven available by round 1's passing bf16-H run).
// ---------------------------------------------------------------------------

#define T_TOK 8192
#define DDIM  1024
#define HDIM  4096
#define NEXP  8

typedef __attribute__((ext_vector_type(8))) short sv8;   // 8 bf16 = 4 VGPR
typedef __attribute__((ext_vector_type(4))) float fv4;   // MFMA acc

__device__ __forceinline__ float gelu_erf(float v) {
    return 0.5f * v * (1.0f + erff(v * 0.70710678118654752f));
}

__device__ __forceinline__ unsigned short f2bfbits(float f) {  // RNE
    unsigned int x; __builtin_memcpy(&x, &f, 4);
    x += 0x7fffu + ((x >> 16) & 1u);
    return (unsigned short)(x >> 16);
}

// split f into hi (bf16 RNE) + lo (bf16 of residual); hi+lo ~ fp32 (~2^-17 rel)
__device__ __forceinline__ void split2(float f, short& h, short& l) {
    unsigned int x; __builtin_memcpy(&x, &f, 4);
    unsigned int hr = x + (0x7fffu + ((x >> 16) & 1u));    // RNE round point
    unsigned int hbits = hr & 0xffff0000u;
    float hf; __builtin_memcpy(&hf, &hbits, 4);
    h = (short)(hr >> 16);
    l = (short)f2bfbits(f - hf);
}

// ---------------------------------------------------------------------------
__global__ __launch_bounds__(256) void zero_kernel(float* __restrict__ out,
                                                   int n, int* __restrict__ counts) {
    int i = blockIdx.x * 256 + threadIdx.x;
    if (i < n) out[i] = 0.0f;
    if (blockIdx.x == 0 && threadIdx.x < 16) counts[threadIdx.x] = 0;
}

__global__ __launch_bounds__(256) void gate_kernel(
    const float* __restrict__ x, const float* __restrict__ gw,
    const float* __restrict__ gb, int* __restrict__ counts,
    int* __restrict__ tok_idx, float* __restrict__ tok_gate) {
    const int token = blockIdx.x * 4 + (threadIdx.x >> 6);
    const int lane  = threadIdx.x & 63;
    const float* xr = x + (size_t)token * DDIM;

    float acc[8] = {0.f, 0.f, 0.f, 0.f, 0.f, 0.f, 0.f, 0.f};
    for (int d = lane; d < DDIM; d += 64) {
        const float xv = xr[d];
        const float4 g0 = *(const float4*)(gw + d * NEXP);
        const float4 g1 = *(const float4*)(gw + d * NEXP + 4);
        acc[0] = fmaf(xv, g0.x, acc[0]); acc[1] = fmaf(xv, g0.y, acc[1]);
        acc[2] = fmaf(xv, g0.z, acc[2]); acc[3] = fmaf(xv, g0.w, acc[3]);
        acc[4] = fmaf(xv, g1.x, acc[4]); acc[5] = fmaf(xv, g1.y, acc[5]);
        acc[6] = fmaf(xv, g1.z, acc[6]); acc[7] = fmaf(xv, g1.w, acc[7]);
    }
#pragma unroll
    for (int e = 0; e < 8; ++e)
        for (int off = 32; off > 0; off >>= 1)
            acc[e] += __shfl_down(acc[e], off);

    if (lane == 0) {
#pragma unroll
        for (int e = 0; e < 8; ++e) acc[e] += gb[e];
        float m = acc[0];
#pragma unroll
        for (int e = 1; e < 8; ++e) m = fmaxf(m, acc[e]);
        float p[8], s = 0.f;
#pragma unroll
        for (int e = 0; e < 8; ++e) { p[e] = expf(acc[e] - m); s += p[e]; }
        const float inv = 1.0f / s;
#pragma unroll
        for (int e = 0; e < 8; ++e) p[e] *= inv;
        int i1 = 0;
#pragma unroll
        for (int e = 1; e < 8; ++e) if (p[e] > p[i1]) i1 = e;
        int i2 = (i1 == 0) ? 1 : 0;
#pragma unroll
        for (int e = 0; e < 8; ++e) if (e != i1 && p[e] > p[i2]) i2 = e;

        int pos1 = atomicAdd(&counts[i1], 1);
        tok_idx[i1 * T_TOK + pos1]  = token;
        tok_gate[i1 * T_TOK + pos1] = p[i1];
        int pos2 = atomicAdd(&counts[i2], 1);
        tok_idx[i2 * T_TOK + pos2]  = token;
        tok_gate[i2 * T_TOK + pos2] = p[i2];
    }
}

__global__ void offs_kernel(const int* __restrict__ counts, int* __restrict__ offs) {
    if (threadIdx.x == 0 && blockIdx.x == 0) {
        int s = 0;
#pragma unroll
        for (int e = 0; e < NEXP; ++e) { offs[e] = s; s += counts[e]; }
        offs[NEXP] = s;
    }
}

// ---------------------------------------------------------------------------
// FFN1: Hbuf[row] = gelu( x[tok[row]] @ w1[e] + b1[e] )   (bf16 out)
__global__ __launch_bounds__(256) void ffn1_mfma(
    const float* __restrict__ x, const float* __restrict__ w1,
    const float* __restrict__ b1, const int* __restrict__ counts,
    const int* __restrict__ offs, const int* __restrict__ tok_idx,
    unsigned short* __restrict__ Hbuf) {
    const int e   = blockIdx.z;
    const int cnt = counts[e];
    const int m0  = blockIdx.y * 128;
    if (m0 >= cnt) return;
    const int n0  = blockIdx.x * 128;

    __shared__ __align__(16) short Ah[128][32], Al[128][32];  // [m][k] bf16
    __shared__ __align__(16) short Bh[128][32], Bl[128][32];  // [n][k] bf16 (w1^T tile)
    __shared__ int stok[128];

    const int tid  = threadIdx.x;
    const int lane = tid & 63;
    const int wv   = tid >> 6;
    const int wr   = wv >> 1, wc = wv & 1;        // wave -> 64x64 subtile
    const int r16  = lane & 15, g4 = lane >> 4;

    if (tid < 128) stok[tid] = tok_idx[e * T_TOK + min(m0 + tid, cnt - 1)];
    __syncthreads();

    const float* W = w1 + (size_t)e * DDIM * HDIM;

    fv4 acc[4][4];
    const fv4 z4 = {0.f, 0.f, 0.f, 0.f};
#pragma unroll
    for (int i = 0; i < 4; ++i)
#pragma unroll
        for (int j = 0; j < 4; ++j) acc[i][j] = z4;

    for (int k0 = 0; k0 < DDIM; k0 += 32) {
        // ---- stage A (gathered x rows, fp32 -> hi/lo bf16) ----
#pragma unroll
        for (int h = 0; h < 2; ++h) {
            const int c   = tid + h * 256;        // chunk id: row = c>>2, kc = c&3
            const int row = c >> 2, kc = c & 3;
            const float* src = x + (size_t)stok[row] * DDIM + k0 + kc * 8;
            const float4 f0 = *(const float4*)src;
            const float4 f1 = *(const float4*)(src + 4);
            const float f[8] = {f0.x, f0.y, f0.z, f0.w, f1.x, f1.y, f1.z, f1.w};
            sv8 hv, lv;
#pragma unroll
            for (int i = 0; i < 8; ++i) { short hh, ll; split2(f[i], hh, ll); hv[i] = hh; lv[i] = ll; }
            *(sv8*)&Ah[row][kc * 8] = hv;
            *(sv8*)&Al[row][kc * 8] = lv;
        }
        // ---- stage B (w1 tile, transpose + fp32 -> hi/lo bf16) ----
#pragma unroll
        for (int h = 0; h < 2; ++h) {
            const int c  = tid + h * 256;
            const int nn = c >> 2, kc = c & 3;
            float f[8];
#pragma unroll
            for (int i = 0; i < 8; ++i)
                f[i] = W[(size_t)(k0 + kc * 8 + i) * HDIM + n0 + nn];
            sv8 hv, lv;
#pragma unroll
            for (int i = 0; i < 8; ++i) { short hh, ll; split2(f[i], hh, ll); hv[i] = hh; lv[i] = ll; }
            *(sv8*)&Bh[nn][kc * 8] = hv;
            *(sv8*)&Bl[nn][kc * 8] = lv;
        }
        __syncthreads();

        // ---- fragments + MFMA (3-term split) ----
        sv8 a_h[4], a_l[4], b_h[4], b_l[4];
#pragma unroll
        for (int m = 0; m < 4; ++m) {
            const int row = wr * 64 + m * 16 + r16;
            a_h[m] = *(const sv8*)&Ah[row][g4 * 8];
            a_l[m] = *(const sv8*)&Al[row][g4 * 8];
        }
#pragma unroll
        for (int n = 0; n < 4; ++n) {
            const int col = wc * 64 + n * 16 + r16;
            b_h[n] = *(const sv8*)&Bh[col][g4 * 8];
            b_l[n] = *(const sv8*)&Bl[col][g4 * 8];
        }
#pragma unroll
        for (int m = 0; m < 4; ++m)
#pragma unroll
            for (int n = 0; n < 4; ++n) {
                acc[m][n] = __builtin_amdgcn_mfma_f32_16x16x32_bf16(a_h[m], b_h[n], acc[m][n], 0, 0, 0);
                acc[m][n] = __builtin_amdgcn_mfma_f32_16x16x32_bf16(a_h[m], b_l[n], acc[m][n], 0, 0, 0);
                acc[m][n] = __builtin_amdgcn_mfma_f32_16x16x32_bf16(a_l[m], b_h[n], acc[m][n], 0, 0, 0);
            }
        __syncthreads();
    }

    // ---- epilogue: bias + GELU -> bf16 H rows ----
    const int hbase = offs[e] + m0;
#pragma unroll
    for (int n = 0; n < 4; ++n) {
        const int colg = n0 + wc * 64 + n * 16 + r16;
        const float bias = b1[e * HDIM + colg];
#pragma unroll
        for (int m = 0; m < 4; ++m) {
#pragma unroll
            for (int r = 0; r < 4; ++r) {
                const int rowl = wr * 64 + m * 16 + g4 * 4 + r;
                if (m0 + rowl < cnt) {
                    const float v = gelu_erf(acc[m][n][r] + bias);
                    Hbuf[(size_t)(hbase + rowl) * HDIM + colg] = f2bfbits(v);
                }
            }
        }
    }
}

// ---------------------------------------------------------------------------
// FFN2: out[tok[row]] += g[row] * ( Hbuf[row] @ w2[e] + b2[e] )
__global__ __launch_bounds__(256) void ffn2_mfma(
    const unsigned short* __restrict__ Hb, const float* __restrict__ w2,
    const float* __restrict__ b2, const int* __restrict__ counts,
    const int* __restrict__ offs, const int* __restrict__ tok_idx,
    const float* __restrict__ tok_gate, float* __restrict__ out) {
    const int e   = blockIdx.z;
    const int cnt = counts[e];
    const int m0  = blockIdx.y * 128;
    if (m0 >= cnt) return;
    const int n0  = blockIdx.x * 128;

    __shared__ __align__(16) short Ahs[128][32];              // H tile (bf16)
    __shared__ __align__(16) short Bh[128][32], Bl[128][32];  // w2^T tile hi/lo
    __shared__ int   stok[128];
    __shared__ float sgate[128];

    const int tid  = threadIdx.x;
    const int lane = tid & 63;
    const int wv   = tid >> 6;
    const int wr   = wv >> 1, wc = wv & 1;
    const int r16  = lane & 15, g4 = lane >> 4;

    if (tid < 128) {
        const int src = e * T_TOK + min(m0 + tid, cnt - 1);
        stok[tid]  = tok_idx[src];
        sgate[tid] = tok_gate[src];
    }
    __syncthreads();

    const float* W = w2 + (size_t)e * HDIM * DDIM;
    const int oe = offs[e];

    fv4 acc[4][4];
    const fv4 z4 = {0.f, 0.f, 0.f, 0.f};
#pragma unroll
    for (int i = 0; i < 4; ++i)
#pragma unroll
        for (int j = 0; j < 4; ++j) acc[i][j] = z4;

    for (int k0 = 0; k0 < HDIM; k0 += 32) {
        // ---- stage A (compact bf16 H rows, direct copy) ----
#pragma unroll
        for (int h = 0; h < 2; ++h) {
            const int c   = tid + h * 256;
            const int row = c >> 2, kc = c & 3;
            const size_t grow = (size_t)(oe + min(m0 + row, cnt - 1));
            *(sv8*)&Ahs[row][kc * 8] = *(const sv8*)(Hb + grow * HDIM + k0 + kc * 8);
        }
        // ---- stage B (w2 tile, transpose + fp32 -> hi/lo bf16) ----
#pragma unroll
        for (int h = 0; h < 2; ++h) {
            const int c  = tid + h * 256;
            const int nn = c >> 2, kc = c & 3;
            float f[8];
#pragma unroll
            for (int i = 0; i < 8; ++i)
                f[i] = W[(size_t)(k0 + kc * 8 + i) * DDIM + n0 + nn];
            sv8 hv, lv;
#pragma unroll
            for (int i = 0; i < 8; ++i) { short hh, ll; split2(f[i], hh, ll); hv[i] = hh; lv[i] = ll; }
            *(sv8*)&Bh[nn][kc * 8] = hv;
            *(sv8*)&Bl[nn][kc * 8] = lv;
        }
        __syncthreads();

        sv8 a[4], b_h[4], b_l[4];
#pragma unroll
        for (int m = 0; m < 4; ++m) {
            const int row = wr * 64 + m * 16 + r16;
            a[m] = *(const sv8*)&Ahs[row][g4 * 8];
        }
#pragma unroll
        for (int n = 0; n < 4; ++n) {
            const int col = wc * 64 + n * 16 + r16;
            b_h[n] = *(const sv8*)&Bh[col][g4 * 8];
            b_l[n] = *(const sv8*)&Bl[col][g4 * 8];
        }
#pragma unroll
        for (int m = 0; m < 4; ++m)
#pragma unroll
            for (int n = 0; n < 4; ++n) {
                acc[m][n] = __builtin_amdgcn_mfma_f32_16x16x32_bf16(a[m], b_h[n], acc[m][n], 0, 0, 0);
                acc[m][n] = __builtin_amdgcn_mfma_f32_16x16x32_bf16(a[m], b_l[n], acc[m][n], 0, 0, 0);
            }
        __syncthreads();
    }

    // ---- epilogue: bias, gate scale, atomic scatter ----
#pragma unroll
    for (int n = 0; n < 4; ++n) {
        const int colg = n0 + wc * 64 + n * 16 + r16;
        const float bias = b2[e * DDIM + colg];
#pragma unroll
        for (int m = 0; m < 4; ++m) {
#pragma unroll
            for (int r = 0; r < 4; ++r) {
                const int rowl = wr * 64 + m * 16 + g4 * 4 + r;
                if (m0 + rowl < cnt) {
                    const int   t  = stok[rowl];
                    const float gg = sgate[rowl];
                    atomicAdd(&out[(size_t)t * DDIM + colg], gg * (acc[m][n][r] + bias));
                }
            }
        }
    }
}

// ---------------------------------------------------------------------------
extern "C" void kernel_launch(void* const* d_in, const int* in_sizes, int n_in,
                              void* d_out, int out_size, void* d_ws, size_t ws_size,
                              hipStream_t stream) {
    const float* x      = (const float*)d_in[0];
    const float* gate_w = (const float*)d_in[1];
    const float* gate_b = (const float*)d_in[2];
    const float* w1     = (const float*)d_in[3];
    const float* b1     = (const float*)d_in[4];
    const float* w2     = (const float*)d_in[5];
    const float* b2     = (const float*)d_in[6];

    char* ws        = (char*)d_ws;
    int*   counts   = (int*)ws;                      // 8 ints
    int*   offs     = (int*)(ws + 64);               // 9 ints
    int*   tok_idx  = (int*)(ws + 1024);             // [E][T] ints, 256KB
    float* tok_gate = (float*)(ws + 1024 + 262144);  // [E][T] floats, 256KB
    unsigned short* Hbuf = (unsigned short*)(ws + (1 << 20));  // [2T][H] bf16, 128MB

    float* out = (float*)d_out;

    zero_kernel<<<(T_TOK * DDIM + 255) / 256, 256, 0, stream>>>(out, T_TOK * DDIM, counts);
    gate_kernel<<<T_TOK / 4, 256, 0, stream>>>(x, gate_w, gate_b, counts, tok_idx, tok_gate);
    offs_kernel<<<1, 64, 0, stream>>>(counts, offs);

    dim3 g1(HDIM / 128, T_TOK / 128, NEXP);  // n-tiles, m-tiles, experts
    dim3 g2(DDIM / 128, T_TOK / 128, NEXP);
    ffn1_mfma<<<g1, 256, 0, stream>>>(x, w1, b1, counts, offs, tok_idx, Hbuf);
    ffn2_mfma<<<g2, 256, 0, stream>>>(Hbuf, w2, b2, counts, offs, tok_idx, tok_gate, out);
}

// Round 9
// 1532.489 us; speedup vs baseline: 2.8037x; 1.1861x over previous
//
#include <hip/hip_runtime.h>
#include <hip/hip_bf16.h>

// ---------------------------------------------------------------------------
// MoE top-2 FFN, MI355X round 9 (= round 7 design, resubmit; 2x infra timeout).
// Split-bf16 MFMA, BM=256 tiles, cvt_pk split, padded LDS.
// T=8192, D=1024, H=4096, E=8, top_k=2, exact-erf GELU.
//
// vs round 6 (measured 1818us, ffn1 VALUBusy 46% >> MfmaUtil 21%):
//   - split2 via __float2bfloat16 (compiler fuses v_cvt_pk_bf16_f32): ~7->3 ops
//   - 256x128 tiles, 512 thr (8 waves x 64x64): staging/MFMA ratio 32->24
//   - LDS rows padded to 40 shorts (80B): frag-read conflicts 8-way -> 2-way
// ws = 1MB meta + 128MB Hbuf (guaranteed fit; ws known >= 129MB, < 269MB).
// ---------------------------------------------------------------------------

#define T_TOK 8192
#define DDIM  1024
#define HDIM  4096
#define NEXP  8

typedef __attribute__((ext_vector_type(8))) short sv8;   // 8 bf16 = 4 VGPR
typedef __attribute__((ext_vector_type(4))) float fv4;   // MFMA acc

__device__ __forceinline__ float gelu_erf(float v) {
    return 0.5f * v * (1.0f + erff(v * 0.70710678118654752f));
}

__device__ __forceinline__ short cvt_bf16(float f) {   // RNE via HW cvt (pairs fuse to v_cvt_pk_bf16_f32)
    __hip_bfloat16 b = __float2bfloat16(f);
    unsigned short s; __builtin_memcpy(&s, &b, 2);
    return (short)s;
}

// split f into hi (bf16 RNE) + lo (bf16 of exact residual); ~3 VALU ops/elem
__device__ __forceinline__ void split2(float f, short& h, short& l) {
    h = cvt_bf16(f);
    unsigned int hb = ((unsigned int)(unsigned short)h) << 16;
    float hf; __builtin_memcpy(&hf, &hb, 4);
    l = cvt_bf16(f - hf);
}

// ---------------------------------------------------------------------------
__global__ __launch_bounds__(256) void zero_kernel(float* __restrict__ out,
                                                   int n, int* __restrict__ counts) {
    int i = blockIdx.x * 256 + threadIdx.x;
    if (i < n) out[i] = 0.0f;
    if (blockIdx.x == 0 && threadIdx.x < 16) counts[threadIdx.x] = 0;
}

__global__ __launch_bounds__(256) void gate_kernel(
    const float* __restrict__ x, const float* __restrict__ gw,
    const float* __restrict__ gb, int* __restrict__ counts,
    int* __restrict__ tok_idx, float* __restrict__ tok_gate) {
    const int token = blockIdx.x * 4 + (threadIdx.x >> 6);
    const int lane  = threadIdx.x & 63;
    const float* xr = x + (size_t)token * DDIM;

    float acc[8] = {0.f, 0.f, 0.f, 0.f, 0.f, 0.f, 0.f, 0.f};
    for (int d = lane; d < DDIM; d += 64) {
        const float xv = xr[d];
        const float4 g0 = *(const float4*)(gw + d * NEXP);
        const float4 g1 = *(const float4*)(gw + d * NEXP + 4);
        acc[0] = fmaf(xv, g0.x, acc[0]); acc[1] = fmaf(xv, g0.y, acc[1]);
        acc[2] = fmaf(xv, g0.z, acc[2]); acc[3] = fmaf(xv, g0.w, acc[3]);
        acc[4] = fmaf(xv, g1.x, acc[4]); acc[5] = fmaf(xv, g1.y, acc[5]);
        acc[6] = fmaf(xv, g1.z, acc[6]); acc[7] = fmaf(xv, g1.w, acc[7]);
    }
#pragma unroll
    for (int e = 0; e < 8; ++e)
        for (int off = 32; off > 0; off >>= 1)
            acc[e] += __shfl_down(acc[e], off);

    if (lane == 0) {
#pragma unroll
        for (int e = 0; e < 8; ++e) acc[e] += gb[e];
        float m = acc[0];
#pragma unroll
        for (int e = 1; e < 8; ++e) m = fmaxf(m, acc[e]);
        float p[8], s = 0.f;
#pragma unroll
        for (int e = 0; e < 8; ++e) { p[e] = expf(acc[e] - m); s += p[e]; }
        const float inv = 1.0f / s;
#pragma unroll
        for (int e = 0; e < 8; ++e) p[e] *= inv;
        int i1 = 0;
#pragma unroll
        for (int e = 1; e < 8; ++e) if (p[e] > p[i1]) i1 = e;
        int i2 = (i1 == 0) ? 1 : 0;
#pragma unroll
        for (int e = 0; e < 8; ++e) if (e != i1 && p[e] > p[i2]) i2 = e;

        int pos1 = atomicAdd(&counts[i1], 1);
        tok_idx[i1 * T_TOK + pos1]  = token;
        tok_gate[i1 * T_TOK + pos1] = p[i1];
        int pos2 = atomicAdd(&counts[i2], 1);
        tok_idx[i2 * T_TOK + pos2]  = token;
        tok_gate[i2 * T_TOK + pos2] = p[i2];
    }
}

__global__ void offs_kernel(const int* __restrict__ counts, int* __restrict__ offs) {
    if (threadIdx.x == 0 && blockIdx.x == 0) {
        int s = 0;
#pragma unroll
        for (int e = 0; e < NEXP; ++e) { offs[e] = s; s += counts[e]; }
        offs[NEXP] = s;
    }
}

// ---------------------------------------------------------------------------
// FFN1: Hbuf[row] = gelu( x[tok[row]] @ w1[e] + b1[e] )  (bf16 out)
// 256x128 tile, 512 thr (8 waves: wr 0..3 x wc 0..1, each 64x64), BK=32.
__global__ __launch_bounds__(512) void ffn1_mfma(
    const float* __restrict__ x, const float* __restrict__ w1,
    const float* __restrict__ b1, const int* __restrict__ counts,
    const int* __restrict__ offs, const int* __restrict__ tok_idx,
    unsigned short* __restrict__ Hbuf) {
    const int e   = blockIdx.z;
    const int cnt = counts[e];
    const int m0  = blockIdx.y * 256;
    if (m0 >= cnt) return;
    const int n0  = blockIdx.x * 128;

    __shared__ __align__(16) short Ah[256][40], Al[256][40];  // [m][k] bf16, 80B rows
    __shared__ __align__(16) short Bh[128][40], Bl[128][40];  // [n][k] bf16 (w1^T tile)
    __shared__ int stok[256];

    const int tid  = threadIdx.x;                 // 0..511
    const int lane = tid & 63;
    const int wv   = tid >> 6;                    // 0..7
    const int wr   = wv >> 1, wc = wv & 1;        // wave -> 64x64 subtile of 256x128
    const int r16  = lane & 15, g4 = lane >> 4;

    if (tid < 256) stok[tid] = tok_idx[e * T_TOK + min(m0 + tid, cnt - 1)];
    __syncthreads();

    const float* W = w1 + (size_t)e * DDIM * HDIM;

    fv4 acc[4][4];
    const fv4 z4 = {0.f, 0.f, 0.f, 0.f};
#pragma unroll
    for (int i = 0; i < 4; ++i)
#pragma unroll
        for (int j = 0; j < 4; ++j) acc[i][j] = z4;

    for (int k0 = 0; k0 < DDIM; k0 += 32) {
        // ---- stage A: 256x32, 2 chunks/thread (gathered x rows, split) ----
#pragma unroll
        for (int h = 0; h < 2; ++h) {
            const int c   = tid + h * 512;        // row = c>>2 (0..255), kc = c&3
            const int row = c >> 2, kc = c & 3;
            const float* src = x + (size_t)stok[row] * DDIM + k0 + kc * 8;
            const float4 f0 = *(const float4*)src;
            const float4 f1 = *(const float4*)(src + 4);
            const float f[8] = {f0.x, f0.y, f0.z, f0.w, f1.x, f1.y, f1.z, f1.w};
            sv8 hv, lv;
#pragma unroll
            for (int i = 0; i < 8; ++i) { short hh, ll; split2(f[i], hh, ll); hv[i] = hh; lv[i] = ll; }
            *(sv8*)&Ah[row][kc * 8] = hv;
            *(sv8*)&Al[row][kc * 8] = lv;
        }
        // ---- stage B: 128x32, 1 chunk/thread (w1 transpose + split) ----
        {
            const int nn = tid >> 2, kc = tid & 3;
            float f[8];
#pragma unroll
            for (int i = 0; i < 8; ++i)
                f[i] = W[(size_t)(k0 + kc * 8 + i) * HDIM + n0 + nn];
            sv8 hv, lv;
#pragma unroll
            for (int i = 0; i < 8; ++i) { short hh, ll; split2(f[i], hh, ll); hv[i] = hh; lv[i] = ll; }
            *(sv8*)&Bh[nn][kc * 8] = hv;
            *(sv8*)&Bl[nn][kc * 8] = lv;
        }
        __syncthreads();

        // ---- fragments + MFMA (3-term split: hh + hl + lh) ----
        sv8 a_h[4], a_l[4], b_h[4], b_l[4];
#pragma unroll
        for (int m = 0; m < 4; ++m) {
            const int row = wr * 64 + m * 16 + r16;
            a_h[m] = *(const sv8*)&Ah[row][g4 * 8];
            a_l[m] = *(const sv8*)&Al[row][g4 * 8];
        }
#pragma unroll
        for (int n = 0; n < 4; ++n) {
            const int col = wc * 64 + n * 16 + r16;
            b_h[n] = *(const sv8*)&Bh[col][g4 * 8];
            b_l[n] = *(const sv8*)&Bl[col][g4 * 8];
        }
#pragma unroll
        for (int m = 0; m < 4; ++m)
#pragma unroll
            for (int n = 0; n < 4; ++n) {
                acc[m][n] = __builtin_amdgcn_mfma_f32_16x16x32_bf16(a_h[m], b_h[n], acc[m][n], 0, 0, 0);
                acc[m][n] = __builtin_amdgcn_mfma_f32_16x16x32_bf16(a_h[m], b_l[n], acc[m][n], 0, 0, 0);
                acc[m][n] = __builtin_amdgcn_mfma_f32_16x16x32_bf16(a_l[m], b_h[n], acc[m][n], 0, 0, 0);
            }
        __syncthreads();
    }

    // ---- epilogue: bias + GELU -> bf16 H rows ----
    const int hbase = offs[e] + m0;
#pragma unroll
    for (int n = 0; n < 4; ++n) {
        const int colg = n0 + wc * 64 + n * 16 + r16;
        const float bias = b1[e * HDIM + colg];
#pragma unroll
        for (int m = 0; m < 4; ++m) {
#pragma unroll
            for (int r = 0; r < 4; ++r) {
                const int rowl = wr * 64 + m * 16 + g4 * 4 + r;
                if (m0 + rowl < cnt) {
                    const float v = gelu_erf(acc[m][n][r] + bias);
                    Hbuf[(size_t)(hbase + rowl) * HDIM + colg] = (unsigned short)cvt_bf16(v);
                }
            }
        }
    }
}

// ---------------------------------------------------------------------------
// FFN2: out[tok[row]] += g[row] * ( Hbuf[row] @ w2[e] + b2[e] )
// 256x128 tile, 512 thr, BK=32. A = bf16 H (copy), B = w2 split, 2-term MFMA.
__global__ __launch_bounds__(512) void ffn2_mfma(
    const unsigned short* __restrict__ Hb, const float* __restrict__ w2,
    const float* __restrict__ b2, const int* __restrict__ counts,
    const int* __restrict__ offs, const int* __restrict__ tok_idx,
    const float* __restrict__ tok_gate, float* __restrict__ out) {
    const int e   = blockIdx.z;
    const int cnt = counts[e];
    const int m0  = blockIdx.y * 256;
    if (m0 >= cnt) return;
    const int n0  = blockIdx.x * 128;

    __shared__ __align__(16) short Ahs[256][40];              // H tile (bf16)
    __shared__ __align__(16) short Bh[128][40], Bl[128][40];  // w2^T tile hi/lo
    __shared__ int   stok[256];
    __shared__ float sgate[256];

    const int tid  = threadIdx.x;
    const int lane = tid & 63;
    const int wv   = tid >> 6;
    const int wr   = wv >> 1, wc = wv & 1;
    const int r16  = lane & 15, g4 = lane >> 4;

    if (tid < 256) {
        const int src = e * T_TOK + min(m0 + tid, cnt - 1);
        stok[tid]  = tok_idx[src];
        sgate[tid] = tok_gate[src];
    }
    __syncthreads();

    const float* W = w2 + (size_t)e * HDIM * DDIM;
    const int oe = offs[e];

    fv4 acc[4][4];
    const fv4 z4 = {0.f, 0.f, 0.f, 0.f};
#pragma unroll
    for (int i = 0; i < 4; ++i)
#pragma unroll
        for (int j = 0; j < 4; ++j) acc[i][j] = z4;

    for (int k0 = 0; k0 < HDIM; k0 += 32) {
        // ---- stage A: 256x32, 2 chunks/thread (compact bf16 H rows, copy) ----
#pragma unroll
        for (int h = 0; h < 2; ++h) {
            const int c   = tid + h * 512;
            const int row = c >> 2, kc = c & 3;
            const size_t grow = (size_t)(oe + min(m0 + row, cnt - 1));
            *(sv8*)&Ahs[row][kc * 8] = *(const sv8*)(Hb + grow * HDIM + k0 + kc * 8);
        }
        // ---- stage B: 128x32, 1 chunk/thread (w2 transpose + split) ----
        {
            const int nn = tid >> 2, kc = tid & 3;
            float f[8];
#pragma unroll
            for (int i = 0; i < 8; ++i)
                f[i] = W[(size_t)(k0 + kc * 8 + i) * DDIM + n0 + nn];
            sv8 hv, lv;
#pragma unroll
            for (int i = 0; i < 8; ++i) { short hh, ll; split2(f[i], hh, ll); hv[i] = hh; lv[i] = ll; }
            *(sv8*)&Bh[nn][kc * 8] = hv;
            *(sv8*)&Bl[nn][kc * 8] = lv;
        }
        __syncthreads();

        sv8 a[4], b_h[4], b_l[4];
#pragma unroll
        for (int m = 0; m < 4; ++m) {
            const int row = wr * 64 + m * 16 + r16;
            a[m] = *(const sv8*)&Ahs[row][g4 * 8];
        }
#pragma unroll
        for (int n = 0; n < 4; ++n) {
            const int col = wc * 64 + n * 16 + r16;
            b_h[n] = *(const sv8*)&Bh[col][g4 * 8];
            b_l[n] = *(const sv8*)&Bl[col][g4 * 8];
        }
#pragma unroll
        for (int m = 0; m < 4; ++m)
#pragma unroll
            for (int n = 0; n < 4; ++n) {
                acc[m][n] = __builtin_amdgcn_mfma_f32_16x16x32_bf16(a[m], b_h[n], acc[m][n], 0, 0, 0);
                acc[m][n] = __builtin_amdgcn_mfma_f32_16x16x32_bf16(a[m], b_l[n], acc[m][n], 0, 0, 0);
            }
        __syncthreads();
    }

    // ---- epilogue: bias, gate scale, atomic scatter ----
#pragma unroll
    for (int n = 0; n < 4; ++n) {
        const int colg = n0 + wc * 64 + n * 16 + r16;
        const float bias = b2[e * DDIM + colg];
#pragma unroll
        for (int m = 0; m < 4; ++m) {
#pragma unroll
            for (int r = 0; r < 4; ++r) {
                const int rowl = wr * 64 + m * 16 + g4 * 4 + r;
                if (m0 + rowl < cnt) {
                    const int   t  = stok[rowl];
                    const float gg = sgate[rowl];
                    atomicAdd(&out[(size_t)t * DDIM + colg], gg * (acc[m][n][r] + bias));
                }
            }
        }
    }
}

// ---------------------------------------------------------------------------
extern "C" void kernel_launch(void* const* d_in, const int* in_sizes, int n_in,
                              void* d_out, int out_size, void* d_ws, size_t ws_size,
                              hipStream_t stream) {
    const float* x      = (const float*)d_in[0];
    const float* gate_w = (const float*)d_in[1];
    const float* gate_b = (const float*)d_in[2];
    const float* w1     = (const float*)d_in[3];
    const float* b1     = (const float*)d_in[4];
    const float* w2     = (const float*)d_in[5];
    const float* b2     = (const float*)d_in[6];

    char* ws        = (char*)d_ws;
    int*   counts   = (int*)ws;                      // 8 ints
    int*   offs     = (int*)(ws + 64);               // 9 ints
    int*   tok_idx  = (int*)(ws + 1024);             // [E][T] ints, 256KB
    float* tok_gate = (float*)(ws + 1024 + 262144);  // [E][T] floats, 256KB
    unsigned short* Hbuf = (unsigned short*)(ws + (1 << 20));  // [2T][H] bf16, 128MB

    float* out = (float*)d_out;

    zero_kernel<<<(T_TOK * DDIM + 255) / 256, 256, 0, stream>>>(out, T_TOK * DDIM, counts);
    gate_kernel<<<T_TOK / 4, 256, 0, stream>>>(x, gate_w, gate_b, counts, tok_idx, tok_gate);
    offs_kernel<<<1, 64, 0, stream>>>(counts, offs);

    dim3 g1(HDIM / 128, T_TOK / 256, NEXP);  // n-tiles, m-tiles (BM=256), experts
    dim3 g2(DDIM / 128, T_TOK / 256, NEXP);
    ffn1_mfma<<<g1, 512, 0, stream>>>(x, w1, b1, counts, offs, tok_idx, Hbuf);
    ffn2_mfma<<<g2, 512, 0, stream>>>(Hbuf, w2, b2, counts, offs, tok_idx, tok_gate, out);
}